// Round 5
// baseline (162.311 us; speedup 1.0000x reference)
//
#include <hip/hip_runtime.h>
#include <math.h>

#define HW_   128
#define CIN_  64
#define IMG_  (HW_ * HW_)       // 16384

// ---- new bf16-staged path: 2 output rows x 32 cols, 6x40 halo, pitch 32 ----
#define TR_    6                // tile rows  [h0-2 .. h0+3]
#define TC_    40               // tile cols  [w0-4 .. w0+35]
#define PIT_   32               // dwords per pixel (64ch bf16, NO pad)
                                // bank conflicts fixed by chunk-XOR swizzle instead
#define TILEDW (TR_ * TC_ * PIT_)   // 7680 dw = 30720 B -> 5 blocks/CU

// ---- fallback f32-staged path (round-3 exact) ----
#define OPIT_  36
#define OTILE  (TR_ * TC_ * OPIT_)  // 8640 dw = 34560 B

#define WOF_BYTES 36864
#define WA_BYTES  73728
#define XB_OFF    (WOF_BYTES + WA_BYTES)              // 110592
#define XB_DW     ((size_t)8 * IMG_ * 32)             // 4,194,304 dwords
#define WS_NEED   (XB_OFF + (XB_DW + 32) * 4)         // + zero record

typedef short    s16x8 __attribute__((ext_vector_type(8)));
typedef float    f32x4 __attribute__((ext_vector_type(4)));
typedef float    f32x2 __attribute__((ext_vector_type(2)));
typedef unsigned u32x4 __attribute__((ext_vector_type(4)));

__device__ __forceinline__ short f2bf(float f) {
  union { float f; unsigned i; } v; v.f = f;
  unsigned r = (v.i + 0x7fffu + ((v.i >> 16) & 1u)) >> 16;   // RNE
  return (short)r;
}

#if defined(__has_builtin)
#if __has_builtin(__builtin_amdgcn_cvt_pk_bf16_f32)
#define HAVE_CVT_PK_BF16 1
#endif
#endif

// pack two f32 -> bf16 pair (lo=a, hi=b)
__device__ __forceinline__ unsigned PK2(float a, float b) {
#ifdef HAVE_CVT_PK_BF16
  typedef __bf16 bf16x2_t __attribute__((ext_vector_type(2)));
  union { bf16x2_t v; unsigned u; } cv;
  cv.v = __builtin_amdgcn_cvt_pk_bf16_f32(a, b);
  return cv.u;
#else
  union { float f; unsigned u; } ua, ub; ua.f = a; ub.f = b;
  unsigned ra = ua.u + 0x7fffu + ((ua.u >> 16) & 1u);
  unsigned rb = ub.u + 0x7fffu + ((ub.u >> 16) & 1u);
  return __builtin_amdgcn_perm(rb, ra, 0x07060302u);
#endif
}

// dirty-hi f32x2 unpack of a bf16 pair: elem0 exact (d<<16), elem1 keeps the
// junk low 16 mantissa bits (rel err ~2^-16, far below the 2^-9 bf16 repack
// rounding). 1 VALU op per dword; blend chains on f32x2 emit v_pk_fma_f32.
__device__ __forceinline__ f32x2 up2d(unsigned d) {
  union { unsigned u; float f; } lo, hi;
  lo.u = d << 16; hi.u = d;
  return (f32x2){lo.f, hi.f};
}

// ws layout (bytes):
//   [0,     36864)   wOf bf16 [j:9][ks:2][q:4][m:32][i:8]  (A-frag order, m>=27 zero)
//   [36864, 110592)  wA  bf16 [j:9][ks:2][q:4][o:64][i:8]  (A-frag order)
//   [110592, +16MB)  xb  bf16 NHWC [img:8][px:16384][ch:64] + 128B zero record

__global__ __launch_bounds__(256) void wprep(const float* __restrict__ w_off,
                                             const float* __restrict__ w_conv,
                                             short* __restrict__ wOf,
                                             short* __restrict__ wA) {
  int t = blockIdx.x * 256 + threadIdx.x;
  if (t < 36864) {
    int i = t & 7, o = (t >> 3) & 63, q = (t >> 9) & 3, ks = (t >> 11) & 1, j = t >> 12;
    int c = ks * 32 + q * 8 + i;
    wA[t] = f2bf(w_conv[o * 576 + c * 9 + j]);
  }
  if (t < 18432) {
    int i = t & 7, m = (t >> 3) & 31, q = (t >> 8) & 3, ks = (t >> 10) & 1, j = t >> 11;
    int c = ks * 32 + q * 8 + i;
    wOf[t] = (m < 27) ? f2bf(w_off[(m * 64 + c) * 9 + j]) : (short)0;
  }
}

// f32 NCHW -> bf16 NHWC, via LDS transpose for coalesced reads AND writes.
// block = (img, row): 1024 blocks. XCD-swizzled by image to match dfuse2.
__global__ __launch_bounds__(256) void xprep(const float* __restrict__ x,
                                             unsigned* __restrict__ xb) {
  __shared__ __align__(16) unsigned xl[128 * 36];   // 18432 B, pitch 36 (b128-aligned)
  int bi  = blockIdx.x & 7;
  int row = blockIdx.x >> 3;
  int t   = threadIdx.x;
  int cp  = t >> 3;        // ch-pair 0..31
  int wq  = t & 7;

  const float* xRow = x + (size_t)bi * (CIN_ * IMG_) + row * HW_;
  const float* s0 = xRow + (2 * cp) * IMG_;
#pragma unroll
  for (int k = 0; k < 4; ++k) {
    float4 f0 = *(const float4*)(s0 + k * 32 + wq * 4);
    float4 f1 = *(const float4*)(s0 + IMG_ + k * 32 + wq * 4);
    int w = k * 32 + wq * 4;
    xl[(w    ) * 36 + cp] = PK2(f0.x, f1.x);
    xl[(w + 1) * 36 + cp] = PK2(f0.y, f1.y);
    xl[(w + 2) * 36 + cp] = PK2(f0.z, f1.z);
    xl[(w + 3) * 36 + cp] = PK2(f0.w, f1.w);
  }
  __syncthreads();

  unsigned* xbI = xb + (size_t)bi * (IMG_ * 32) + (size_t)row * (HW_ * 32);
#pragma unroll
  for (int k = 0; k < 4; ++k) {
    int i = t + k * 256;        // (px, chunk), chunk fastest -> coalesced stores
    int px = i >> 3, chunk = i & 7;
    u32x4 v = *(const u32x4*)(xl + px * 36 + chunk * 4);
    *(u32x4*)(xbI + (size_t)px * 32 + chunk * 4) = v;
  }
  if (blockIdx.x == 0 && t < 32) xb[XB_DW + t] = 0u;   // zero record
}

// Fused kernel, bf16-staged: copy xb tiles into swizzled LDS (zero-masked OOB,
// one barrier), offset conv (MFMA), shuffle-exchange, LDS-gather sampling +
// MFMA GEMM (bf16 global fallback for |o|>=1).
// LDS chunk swizzle: chunk' = chunk ^ (c&7)  (c = tile col; 40%8==0 so
// px&7 == c&7). Makes staging writes / phase-1 / phase-3 b128 ops
// conflict-optimal at pitch 32. ks1 chunk address = ks0 address ^ 16 dw.
__global__ __launch_bounds__(256)
__attribute__((amdgpu_waves_per_eu(5)))
void dfuse2(const unsigned* __restrict__ xb,
            const short* __restrict__ wOf,
            const float* __restrict__ b_off,
            const short* __restrict__ wA,
            float* __restrict__ out) {
  __shared__ __align__(16) unsigned lds_[TILEDW];

  int bi  = blockIdx.x & 7;        // XCD-aligned image index
  int tid = blockIdx.x >> 3;       // 0..255 tile within image
  int h0  = (tid >> 2) << 1;       // 0,2,..,126
  int w0  = (tid & 3) << 5;        // 0,32,64,96
  int t   = threadIdx.x;
  int wv  = t >> 6, l = t & 63;
  int col = l & 15, q = l >> 4;
  int px_local = wv * 16 + col;    // 0..63
  int rl  = px_local >> 5;         // local row 0..1
  int cl  = px_local & 31;         // local col 0..31
  int h   = h0 + rl;
  int w   = w0 + cl;
  int p   = h * HW_ + w;

  const unsigned* xbB = xb + (size_t)bi * (IMG_ * 32);

  // ---- stage halo tile: pure 16B bf16 copies, swizzled LDS dest ----
  for (int u = t; u < TR_ * TC_ * 8; u += 256) {   // 1920 units
    int chunk = u & 7, pxl = u >> 3;
    int r = pxl / TC_, c = pxl % TC_;
    int y  = h0 - 2 + r;
    int ys = min(max(y, 0), HW_ - 1);
    int xg = w0 - 4 + c;
    int xs = min(max(xg, 0), HW_ - 1);
    bool ok = (y >= 0) && (y < HW_) && (xg >= 0) && (xg < HW_);
    u32x4 v = *(const u32x4*)(xbB + (size_t)(ys * HW_ + xs) * 32 + (chunk << 2));
    if (!ok) v = (u32x4){0u, 0u, 0u, 0u};
    *(u32x4*)(lds_ + pxl * PIT_ + ((chunk ^ (c & 7)) << 2)) = v;
  }
  __syncthreads();

  // ---- phase 1: offset conv from tile (tile is zero-padded: no masking) ----
  float oall[32];
  {
    const short* wq_ = wOf + q * 256 + col * 8;
    f32x4 a0v = {0.f, 0.f, 0.f, 0.f};
    f32x4 a1v = {0.f, 0.f, 0.f, 0.f};
    const unsigned* tbp = lds_ + ((rl + 2) * TC_ + (cl + 4)) * PIT_;
#pragma unroll
    for (int j = 0; j < 9; ++j) {
      int dy = j / 3 - 1, dx = j % 3 - 1;
      int ca = (q ^ ((cl + 4 + dx) & 7)) << 2;
      const unsigned* pb = tbp + (dy * TC_ + dx) * PIT_;
      union { u32x4 u; s16x8 v; } B0, B1;
      B0.u = *(const u32x4*)(pb + ca);
      B1.u = *(const u32x4*)(pb + (ca ^ 16));
      const short* wj = wq_ + j * 2048;
      s16x8 a00 = *(const s16x8*)(wj);
      s16x8 a01 = *(const s16x8*)(wj + 128);
      s16x8 a10 = *(const s16x8*)(wj + 1024);
      s16x8 a11 = *(const s16x8*)(wj + 1024 + 128);
      a0v = __builtin_amdgcn_mfma_f32_16x16x32_bf16(a00, B0.v, a0v, 0, 0, 0);
      a1v = __builtin_amdgcn_mfma_f32_16x16x32_bf16(a01, B0.v, a1v, 0, 0, 0);
      a0v = __builtin_amdgcn_mfma_f32_16x16x32_bf16(a10, B1.v, a0v, 0, 0, 0);
      a1v = __builtin_amdgcn_mfma_f32_16x16x32_bf16(a11, B1.v, a1v, 0, 0, 0);
    }
    float myv[8];
#pragma unroll
    for (int r = 0; r < 4; ++r) myv[r] = a0v[r] + b_off[q * 4 + r];
#pragma unroll
    for (int r = 0; r < 4; ++r) {
      int ch = 16 + q * 4 + r;
      float bo = b_off[min(ch, 26)];
      float v = a1v[r] + bo;
      myv[4 + r] = (ch >= 18) ? (1.f / (1.f + __expf(-v))) : v;
    }
#pragma unroll
    for (int qq = 0; qq < 4; ++qq) {
      int src = qq * 16 + col;
#pragma unroll
      for (int r = 0; r < 4; ++r) {
        oall[qq * 4 + r]      = __shfl(myv[r], src);
        oall[16 + qq * 4 + r] = __shfl(myv[4 + r], src);
      }
    }
  }

  // ---- phase 3: LDS-gather sampling + MFMA GEMM ----
  f32x4 acc[4];
#pragma unroll
  for (int ms = 0; ms < 4; ++ms) acc[ms] = (f32x4){0.f, 0.f, 0.f, 0.f};

  const short* wqA = wA + q * 512 + col * 8;

#pragma unroll
  for (int j = 0; j < 9; ++j) {
    float o1 = oall[j], o2 = oall[9 + j], mk = oall[18 + j];

    float pxf = o1 + (float)(w + (j % 3) - 1);
    float pyf = o2 + (float)(h + (j / 3) - 1);
    float fx = floorf(pxf), fy = floorf(pyf);
    int   x0 = (int)fx,   y0 = (int)fy;
    float ax = pxf - fx, ay = pyf - fy;
    float bx = 1.f - ax, by = 1.f - ay;

    bx = (x0 >= 0  && x0 < HW_)     ? bx : 0.f;
    ax = (x0 >= -1 && x0 < HW_ - 1) ? ax : 0.f;
    by = (y0 >= 0  && y0 < HW_)     ? by : 0.f;
    ay = (y0 >= -1 && y0 < HW_ - 1) ? ay : 0.f;
    float bym = by * mk, aym = ay * mk;
    float u00 = bym * bx, u01 = bym * ax;
    float u10 = aym * bx, u11 = aym * ax;
    f32x2 U00 = {u00, u00}, U01 = {u01, u01};
    f32x2 U10 = {u10, u10}, U11 = {u11, u11};

    u32x4 A00, A01, A10, A11, B00, B01, B10, B11;
    bool intile = (o1 >= -1.f) && (o1 < 1.f) && (o2 >= -1.f) && (o2 < 1.f);
    if (intile) {
      // r0 in [0,4], c0 in [2,36]: no clamps; swizzled chunk addressing.
      int r0 = y0 - (h0 - 2), c0 = x0 - (w0 - 4);
      const unsigned* b00 = lds_ + (r0 * TC_ + c0) * PIT_;
      int s0 = (q ^ (c0 & 7)) << 2;
      int s1 = (q ^ ((c0 + 1) & 7)) << 2;
      A00 = *(const u32x4*)(b00 + s0);
      A01 = *(const u32x4*)(b00 + PIT_ + s1);
      A10 = *(const u32x4*)(b00 + TC_ * PIT_ + s0);
      A11 = *(const u32x4*)(b00 + TC_ * PIT_ + PIT_ + s1);
      B00 = *(const u32x4*)(b00 + (s0 ^ 16));
      B01 = *(const u32x4*)(b00 + PIT_ + (s1 ^ 16));
      B10 = *(const u32x4*)(b00 + TC_ * PIT_ + (s0 ^ 16));
      B11 = *(const u32x4*)(b00 + TC_ * PIT_ + PIT_ + (s1 ^ 16));
    } else {
      // rare fallback: gather bf16 straight from linear xb (clamps only here)
      int xc0 = min(max(x0, 0), HW_ - 1), xc1 = min(max(x0 + 1, 0), HW_ - 1);
      int yc0 = min(max(y0, 0), HW_ - 1), yc1 = min(max(y0 + 1, 0), HW_ - 1);
      const unsigned* g00 = xbB + (size_t)(yc0 * HW_ + xc0) * 32 + (q << 2);
      const unsigned* g01 = xbB + (size_t)(yc0 * HW_ + xc1) * 32 + (q << 2);
      const unsigned* g10 = xbB + (size_t)(yc1 * HW_ + xc0) * 32 + (q << 2);
      const unsigned* g11 = xbB + (size_t)(yc1 * HW_ + xc1) * 32 + (q << 2);
      A00 = *(const u32x4*)g00; B00 = *(const u32x4*)(g00 + 16);
      A01 = *(const u32x4*)g01; B01 = *(const u32x4*)(g01 + 16);
      A10 = *(const u32x4*)g10; B10 = *(const u32x4*)(g10 + 16);
      A11 = *(const u32x4*)g11; B11 = *(const u32x4*)(g11 + 16);
    }

    unsigned F0u[4], F1u[4];
#pragma unroll
    for (int i = 0; i < 4; ++i) {
      f32x2 v0 = up2d(A00[i]) * U00 + up2d(A01[i]) * U01
               + up2d(A10[i]) * U10 + up2d(A11[i]) * U11;   // v_pk_fma_f32
      F0u[i] = PK2(v0.x, v0.y);
      f32x2 v1 = up2d(B00[i]) * U00 + up2d(B01[i]) * U01
               + up2d(B10[i]) * U10 + up2d(B11[i]) * U11;
      F1u[i] = PK2(v1.x, v1.y);
    }

    union { unsigned u[4]; s16x8 v; } F0, F1;
#pragma unroll
    for (int i = 0; i < 4; ++i) { F0.u[i] = F0u[i]; F1.u[i] = F1u[i]; }

    const short* wj = wqA + j * 4096;
#pragma unroll
    for (int ms = 0; ms < 4; ++ms) {
      s16x8 a0 = *(const s16x8*)(wj + ms * 128);
      acc[ms] = __builtin_amdgcn_mfma_f32_16x16x32_bf16(a0, F0.v, acc[ms], 0, 0, 0);
    }
#pragma unroll
    for (int ms = 0; ms < 4; ++ms) {
      s16x8 a1 = *(const s16x8*)(wj + 2048 + ms * 128);
      acc[ms] = __builtin_amdgcn_mfma_f32_16x16x32_bf16(a1, F1.v, acc[ms], 0, 0, 0);
    }
  }

  float* op = out + (size_t)bi * (CIN_ * IMG_) + p;
#pragma unroll
  for (int ms = 0; ms < 4; ++ms)
#pragma unroll
    for (int r = 0; r < 4; ++r)
      op[(ms * 16 + q * 4 + r) * IMG_] = acc[ms][r];
}

// ---------- fallback: round-3 kernel verbatim (f32 staging, pitch 36) ----------
__global__ __launch_bounds__(256)
__attribute__((amdgpu_waves_per_eu(4)))
void dfuse_f32(const float* __restrict__ x,
               const short* __restrict__ wOf,
               const float* __restrict__ b_off,
               const short* __restrict__ wA,
               float* __restrict__ out) {
  __shared__ __align__(16) unsigned lds_[OTILE];

  int bi  = blockIdx.x & 7;
  int tid = blockIdx.x >> 3;
  int h0  = (tid >> 2) << 1;
  int w0  = (tid & 3) << 5;
  int t   = threadIdx.x;
  int wv  = t >> 6, l = t & 63;
  int col = l & 15, q = l >> 4;
  int px_local = wv * 16 + col;
  int rl  = px_local >> 5;
  int cl  = px_local & 31;
  int h   = h0 + rl;
  int w   = w0 + cl;
  int p   = h * HW_ + w;

  const float* xB = x + (size_t)bi * (CIN_ * IMG_);

  for (int u = t; u < TR_ * 32 * 10; u += 256) {
    int cc = u % 10;
    int rc = u / 10;
    int cp = rc & 31;
    int r  = rc >> 5;
    int y  = h0 - 2 + r;
    int ys = min(max(y, 0), HW_ - 1);
    int xg0 = w0 - 4 + cc * 4;
    int xs  = min(max(xg0, 0), HW_ - 4);
    bool ok = (y >= 0) && (y < HW_) && (xg0 >= 0) && (xg0 < HW_);
    const float* s0 = xB + (2 * cp) * IMG_ + ys * HW_ + xs;
    float4 f0 = *(const float4*)s0;
    float4 f1 = *(const float4*)(s0 + IMG_);
    int sd = (r * TC_ + cc * 4) * OPIT_ + cp;
    lds_[sd]             = ok ? PK2(f0.x, f1.x) : 0u;
    lds_[sd + OPIT_]     = ok ? PK2(f0.y, f1.y) : 0u;
    lds_[sd + 2 * OPIT_] = ok ? PK2(f0.z, f1.z) : 0u;
    lds_[sd + 3 * OPIT_] = ok ? PK2(f0.w, f1.w) : 0u;
  }
  __syncthreads();

  float oall[32];
  {
    const short* wq = wOf + q * 256 + col * 8;
    f32x4 a0v = {0.f, 0.f, 0.f, 0.f};
    f32x4 a1v = {0.f, 0.f, 0.f, 0.f};
    const unsigned* tb = &lds_[((rl + 2) * TC_ + (cl + 4)) * OPIT_ + q * 4];
#pragma unroll
    for (int j = 0; j < 9; ++j) {
      int dy = j / 3 - 1, dx = j % 3 - 1;
      const unsigned* tp = tb + (dy * TC_ + dx) * OPIT_;
      union { u32x4 u; s16x8 v; } B0, B1;
      B0.u = *(const u32x4*)tp;
      B1.u = *(const u32x4*)(tp + 16);
      const short* wj = wq + j * 2048;
      s16x8 a00 = *(const s16x8*)(wj);
      s16x8 a01 = *(const s16x8*)(wj + 128);
      s16x8 a10 = *(const s16x8*)(wj + 1024);
      s16x8 a11 = *(const s16x8*)(wj + 1024 + 128);
      a0v = __builtin_amdgcn_mfma_f32_16x16x32_bf16(a00, B0.v, a0v, 0, 0, 0);
      a1v = __builtin_amdgcn_mfma_f32_16x16x32_bf16(a01, B0.v, a1v, 0, 0, 0);
      a0v = __builtin_amdgcn_mfma_f32_16x16x32_bf16(a10, B1.v, a0v, 0, 0, 0);
      a1v = __builtin_amdgcn_mfma_f32_16x16x32_bf16(a11, B1.v, a1v, 0, 0, 0);
    }
    float myv[8];
#pragma unroll
    for (int r = 0; r < 4; ++r) myv[r] = a0v[r] + b_off[q * 4 + r];
#pragma unroll
    for (int r = 0; r < 4; ++r) {
      int ch = 16 + q * 4 + r;
      float bo = b_off[min(ch, 26)];
      float v = a1v[r] + bo;
      myv[4 + r] = (ch >= 18) ? (1.f / (1.f + __expf(-v))) : v;
    }
#pragma unroll
    for (int qq = 0; qq < 4; ++qq) {
      int src = qq * 16 + col;
#pragma unroll
      for (int r = 0; r < 4; ++r) {
        oall[qq * 4 + r]      = __shfl(myv[r], src);
        oall[16 + qq * 4 + r] = __shfl(myv[4 + r], src);
      }
    }
  }

  f32x4 acc[4];
#pragma unroll
  for (int ms = 0; ms < 4; ++ms) acc[ms] = (f32x4){0.f, 0.f, 0.f, 0.f};

  const short* wqA = wA + q * 512 + col * 8;

#pragma unroll
  for (int j = 0; j < 9; ++j) {
    float o1 = oall[j], o2 = oall[9 + j], mk = oall[18 + j];

    float pxf = o1 + (float)(w + (j % 3) - 1);
    float pyf = o2 + (float)(h + (j / 3) - 1);
    float fx = floorf(pxf), fy = floorf(pyf);
    int   x0 = (int)fx,   y0 = (int)fy;
    float ax = pxf - fx, ay = pyf - fy;
    float bx = 1.f - ax, by = 1.f - ay;

    bx = (x0 >= 0  && x0 < HW_)     ? bx : 0.f;
    ax = (x0 >= -1 && x0 < HW_ - 1) ? ax : 0.f;
    by = (y0 >= 0  && y0 < HW_)     ? by : 0.f;
    ay = (y0 >= -1 && y0 < HW_ - 1) ? ay : 0.f;
    float bym = by * mk, aym = ay * mk;
    float u00 = bym * bx, u01 = bym * ax;
    float u10 = aym * bx, u11 = aym * ax;
    f32x2 U00 = {u00, u00}, U01 = {u01, u01};
    f32x2 U10 = {u10, u10}, U11 = {u11, u11};

    unsigned F0u[4], F1u[4];
    bool intile = (o1 >= -1.f) && (o1 < 1.f) && (o2 >= -1.f) && (o2 < 1.f);
    if (intile) {
      int r0 = y0 - (h0 - 2), c0 = x0 - (w0 - 4);
      const unsigned* t00 = &lds_[(r0 * TC_ + c0) * OPIT_ + q * 4];
      u32x4 A00 = *(const u32x4*)(t00);
      u32x4 A01 = *(const u32x4*)(t00 + OPIT_);
      u32x4 A10 = *(const u32x4*)(t00 + TC_ * OPIT_);
      u32x4 A11 = *(const u32x4*)(t00 + TC_ * OPIT_ + OPIT_);
      u32x4 B00 = *(const u32x4*)(t00 + 16);
      u32x4 B01 = *(const u32x4*)(t00 + OPIT_ + 16);
      u32x4 B10 = *(const u32x4*)(t00 + TC_ * OPIT_ + 16);
      u32x4 B11 = *(const u32x4*)(t00 + TC_ * OPIT_ + OPIT_ + 16);
#pragma unroll
      for (int i = 0; i < 4; ++i) {
        f32x2 v0 = up2d(A00[i]) * U00 + up2d(A01[i]) * U01
                 + up2d(A10[i]) * U10 + up2d(A11[i]) * U11;
        F0u[i] = PK2(v0.x, v0.y);
        f32x2 v1 = up2d(B00[i]) * U00 + up2d(B01[i]) * U01
                 + up2d(B10[i]) * U10 + up2d(B11[i]) * U11;
        F1u[i] = PK2(v1.x, v1.y);
      }
    } else {
      int xc0 = min(max(x0, 0), HW_ - 1), xc1 = min(max(x0 + 1, 0), HW_ - 1);
      int yc0 = min(max(y0, 0), HW_ - 1), yc1 = min(max(y0 + 1, 0), HW_ - 1);
      int g00 = yc0 * HW_ + xc0, g01 = yc0 * HW_ + xc1;
      int g10 = yc1 * HW_ + xc0, g11 = yc1 * HW_ + xc1;
      for (int hB = 0; hB < 2; ++hB) {
        for (int ii = 0; ii < 4; ++ii) {
          int c0i = hB * 32 + q * 8 + 2 * ii;
          const float* pc = xB + c0i * IMG_;
          const float* pd = pc + IMG_;
          float va = u00 * pc[g00] + u01 * pc[g01] + u10 * pc[g10] + u11 * pc[g11];
          float vb = u00 * pd[g00] + u01 * pd[g01] + u10 * pd[g10] + u11 * pd[g11];
          if (hB) F1u[ii] = PK2(va, vb); else F0u[ii] = PK2(va, vb);
        }
      }
    }

    union { unsigned u[4]; s16x8 v; } F0, F1;
#pragma unroll
    for (int i = 0; i < 4; ++i) { F0.u[i] = F0u[i]; F1.u[i] = F1u[i]; }

    const short* wj = wqA + j * 4096;
#pragma unroll
    for (int ms = 0; ms < 4; ++ms) {
      s16x8 a0 = *(const s16x8*)(wj + ms * 128);
      acc[ms] = __builtin_amdgcn_mfma_f32_16x16x32_bf16(a0, F0.v, acc[ms], 0, 0, 0);
    }
#pragma unroll
    for (int ms = 0; ms < 4; ++ms) {
      s16x8 a1 = *(const s16x8*)(wj + 2048 + ms * 128);
      acc[ms] = __builtin_amdgcn_mfma_f32_16x16x32_bf16(a1, F1.v, acc[ms], 0, 0, 0);
    }
  }

  float* op = out + (size_t)bi * (CIN_ * IMG_) + p;
#pragma unroll
  for (int ms = 0; ms < 4; ++ms)
#pragma unroll
    for (int r = 0; r < 4; ++r)
      op[(ms * 16 + q * 4 + r) * IMG_] = acc[ms][r];
}

extern "C" void kernel_launch(void* const* d_in, const int* in_sizes, int n_in,
                              void* d_out, int out_size, void* d_ws, size_t ws_size,
                              hipStream_t stream) {
  const float* x      = (const float*)d_in[0];
  const float* w_off  = (const float*)d_in[1];
  const float* b_off  = (const float*)d_in[2];
  const float* w_conv = (const float*)d_in[3];
  float* out = (float*)d_out;

  char* ws = (char*)d_ws;
  short* wOf = (short*)(ws);
  short* wA  = (short*)(ws + WOF_BYTES);

  hipLaunchKernelGGL(wprep, dim3(144), dim3(256), 0, stream, w_off, w_conv, wOf, wA);

  if (ws_size >= WS_NEED) {
    unsigned* xb = (unsigned*)(ws + XB_OFF);
    hipLaunchKernelGGL(xprep,  dim3(1024), dim3(256), 0, stream, x, xb);
    hipLaunchKernelGGL(dfuse2, dim3(2048), dim3(256), 0, stream, xb, wOf, b_off, wA, out);
  } else {
    hipLaunchKernelGGL(dfuse_f32, dim3(2048), dim3(256), 0, stream, x, wOf, b_off, wA, out);
  }
}

// Round 6
// 126.364 us; speedup vs baseline: 1.2845x; 1.2845x over previous
//
#include <hip/hip_runtime.h>
#include <math.h>

#define HW_   128
#define CIN_  64
#define IMG_  (HW_ * HW_)       // 16384

// 2 output rows x 32 output cols per block
#define TR_    6                // tile rows  [h0-2 .. h0+3]
#define TC_    40               // tile cols  [w0-4 .. w0+35]
#define PIT_   36               // dwords per pixel (64ch bf16 = 32 dw + 4 pad)
                                // MUST be mult of 4: keeps every u32x4 LDS access 16B-aligned
#define TILEDW (TR_ * TC_ * PIT_)   // 8640 dw = 34560 B -> 4 blocks/CU
#define NUNITS (TR_ * 32 * 10)      // 1920 staging units

typedef short    s16x8 __attribute__((ext_vector_type(8)));
typedef float    f32x4 __attribute__((ext_vector_type(4)));
typedef float    f32x2 __attribute__((ext_vector_type(2)));
typedef unsigned u32x4 __attribute__((ext_vector_type(4)));

__device__ __forceinline__ short f2bf(float f) {
  union { float f; unsigned i; } v; v.f = f;
  unsigned r = (v.i + 0x7fffu + ((v.i >> 16) & 1u)) >> 16;   // RNE
  return (short)r;
}

#if defined(__has_builtin)
#if __has_builtin(__builtin_amdgcn_cvt_pk_bf16_f32)
#define HAVE_CVT_PK_BF16 1
#endif
#endif

// pack two f32 -> bf16 pair (lo=a, hi=b)
__device__ __forceinline__ unsigned PK2(float a, float b) {
#ifdef HAVE_CVT_PK_BF16
  typedef __bf16 bf16x2_t __attribute__((ext_vector_type(2)));
  union { bf16x2_t v; unsigned u; } cv;
  cv.v = __builtin_amdgcn_cvt_pk_bf16_f32(a, b);
  return cv.u;
#else
  union { float f; unsigned u; } ua, ub; ua.f = a; ub.f = b;
  unsigned ra = ua.u + 0x7fffu + ((ua.u >> 16) & 1u);
  unsigned rb = ub.u + 0x7fffu + ((ub.u >> 16) & 1u);
  return __builtin_amdgcn_perm(rb, ra, 0x07060302u);
#endif
}

// dirty-hi f32x2 unpack of a bf16 pair: elem0 exact (d<<16), elem1 keeps the
// junk low 16 mantissa bits (rel err ~2^-16, far below the 2^-9 bf16 repack
// rounding). 1 VALU op per dword; blend chains on f32x2 emit v_pk_fma_f32.
__device__ __forceinline__ f32x2 up2d(unsigned d) {
  union { unsigned u; float f; } lo, hi;
  lo.u = d << 16; hi.u = d;
  return (f32x2){lo.f, hi.f};
}

// ws layout (bytes):
//   [0,     36864)  wOf bf16 [j:9][ks:2][q:4][m:32][i:8]  (A-frag order, m>=27 zero)
//   [36864, 110592) wA  bf16 [j:9][ks:2][q:4][o:64][i:8]  (A-frag order)

__global__ __launch_bounds__(256) void wprep(const float* __restrict__ w_off,
                                             const float* __restrict__ w_conv,
                                             short* __restrict__ wOf,
                                             short* __restrict__ wA) {
  int t = blockIdx.x * 256 + threadIdx.x;
  if (t < 36864) {
    int i = t & 7, o = (t >> 3) & 63, q = (t >> 9) & 3, ks = (t >> 11) & 1, j = t >> 12;
    int c = ks * 32 + q * 8 + i;
    wA[t] = f2bf(w_conv[o * 576 + c * 9 + j]);
  }
  if (t < 18432) {
    int i = t & 7, m = (t >> 3) & 31, q = (t >> 8) & 3, ks = (t >> 10) & 1, j = t >> 11;
    int c = ks * 32 + q * 8 + i;
    wOf[t] = (m < 27) ? f2bf(w_off[(m * 64 + c) * 9 + j]) : (short)0;
  }
}

// Fully fused (round-3 structure): stage f32 NCHW -> bf16 NHWC halo tile in
// LDS (zero-filled OOB, one barrier), offset conv (MFMA), shuffle-exchange
// offsets, LDS-gather sampling + MFMA GEMM (f32 global fallback for |o|>=1).
// Round-6 deltas: (a) T14 batched staging: issue 8 global loads before any
// convert/ds_write (2 batches of 4 units) so the pre-barrier chain costs
// ~2 load-latencies instead of ~7.5; (b) split MFMA accumulator chains
// (two banks, merged at the end) to halve dependency depth.
__global__ __launch_bounds__(256)
__attribute__((amdgpu_waves_per_eu(4)))
void dfuse(const float* __restrict__ x,
           const short* __restrict__ wOf,
           const float* __restrict__ b_off,
           const short* __restrict__ wA,
           float* __restrict__ out) {
  __shared__ __align__(16) unsigned lds_[TILEDW];

  int bi  = blockIdx.x & 7;        // XCD-aligned image index
  int tid = blockIdx.x >> 3;       // 0..255 tile within image
  int h0  = (tid >> 2) << 1;       // 0,2,..,126
  int w0  = (tid & 3) << 5;        // 0,32,64,96
  int t   = threadIdx.x;
  int wv  = t >> 6, l = t & 63;
  int col = l & 15, q = l >> 4;
  int px_local = wv * 16 + col;    // 0..63
  int rl  = px_local >> 5;         // local row 0..1
  int cl  = px_local & 31;         // local col 0..31
  int h   = h0 + rl;
  int w   = w0 + cl;
  int p   = h * HW_ + w;

  const float* xB = x + (size_t)bi * (CIN_ * IMG_);

  // ---- stage halo tile: rows h0-2..h0+3, cols w0-4..w0+35, 64 ch bf16 ----
  // T14 batched: issue 4 units' loads (8 float4 in flight), then convert+write.
  // OOB positions stored as ZERO via branchless &mask.
#pragma unroll
  for (int half = 0; half < 2; ++half) {
    float4   f0s[4], f1s[4];
    int      sds[4];
    unsigned okm[4];
#pragma unroll
    for (int k = 0; k < 4; ++k) {
      int u  = t + (half * 4 + k) * 256;
      int uu = (u < NUNITS) ? u : 0;           // dead lanes load unit 0 (safe)
      int cc = uu % 10;
      int rc = uu / 10;
      int cp = rc & 31;
      int r  = rc >> 5;
      int y  = h0 - 2 + r;
      int ys = min(max(y, 0), HW_ - 1);
      int xg0 = w0 - 4 + cc * 4;
      int xs  = min(max(xg0, 0), HW_ - 4);     // stays 16B-aligned
      bool ok = (y >= 0) && (y < HW_) && (xg0 >= 0) && (xg0 < HW_);
      const float* s0 = xB + (2 * cp) * IMG_ + ys * HW_ + xs;
      f0s[k] = *(const float4*)s0;             // ch 2cp
      f1s[k] = *(const float4*)(s0 + IMG_);    // ch 2cp+1
      sds[k] = (r * TC_ + cc * 4) * PIT_ + cp;
      okm[k] = ok ? 0xffffffffu : 0u;
    }
#pragma unroll
    for (int k = 0; k < 4; ++k) {
      int u = t + (half * 4 + k) * 256;
      if (u < NUNITS) {                        // wave-uniform guard
        int sd = sds[k];
        unsigned m = okm[k];
        lds_[sd]            = PK2(f0s[k].x, f1s[k].x) & m;
        lds_[sd + PIT_]     = PK2(f0s[k].y, f1s[k].y) & m;
        lds_[sd + 2 * PIT_] = PK2(f0s[k].z, f1s[k].z) & m;
        lds_[sd + 3 * PIT_] = PK2(f0s[k].w, f1s[k].w) & m;
      }
    }
  }
  __syncthreads();

  // ---- phase 1: offset conv from tile (tile is zero-padded: no masking) ----
  float oall[32];
  {
    const short* wq = wOf + q * 256 + col * 8;
    f32x4 a0v = {0.f, 0.f, 0.f, 0.f};
    f32x4 a1v = {0.f, 0.f, 0.f, 0.f};
    f32x4 a0w = {0.f, 0.f, 0.f, 0.f};
    f32x4 a1w = {0.f, 0.f, 0.f, 0.f};
    const unsigned* tb = &lds_[((rl + 2) * TC_ + (cl + 4)) * PIT_ + q * 4];
#pragma unroll
    for (int j = 0; j < 9; ++j) {
      int dy = j / 3 - 1, dx = j % 3 - 1;
      const unsigned* tp = tb + (dy * TC_ + dx) * PIT_;   // compile-time imm
      union { u32x4 u; s16x8 v; } B0, B1;
      B0.u = *(const u32x4*)tp;
      B1.u = *(const u32x4*)(tp + 16);
      const short* wj = wq + j * 2048;
      s16x8 a00 = *(const s16x8*)(wj);
      s16x8 a01 = *(const s16x8*)(wj + 128);
      s16x8 a10 = *(const s16x8*)(wj + 1024);
      s16x8 a11 = *(const s16x8*)(wj + 1024 + 128);
      a0v = __builtin_amdgcn_mfma_f32_16x16x32_bf16(a00, B0.v, a0v, 0, 0, 0);
      a1v = __builtin_amdgcn_mfma_f32_16x16x32_bf16(a01, B0.v, a1v, 0, 0, 0);
      a0w = __builtin_amdgcn_mfma_f32_16x16x32_bf16(a10, B1.v, a0w, 0, 0, 0);
      a1w = __builtin_amdgcn_mfma_f32_16x16x32_bf16(a11, B1.v, a1w, 0, 0, 0);
    }
    a0v += a0w;
    a1v += a1w;
    // bias + sigmoid by producer lanes, then wave-local shuffle exchange
    float myv[8];
#pragma unroll
    for (int r = 0; r < 4; ++r) myv[r] = a0v[r] + b_off[q * 4 + r];
#pragma unroll
    for (int r = 0; r < 4; ++r) {
      int ch = 16 + q * 4 + r;
      float bo = b_off[min(ch, 26)];
      float v = a1v[r] + bo;
      myv[4 + r] = (ch >= 18) ? (1.f / (1.f + __expf(-v))) : v;
    }
#pragma unroll
    for (int qq = 0; qq < 4; ++qq) {
      int src = qq * 16 + col;
#pragma unroll
      for (int r = 0; r < 4; ++r) {
        oall[qq * 4 + r]      = __shfl(myv[r], src);
        oall[16 + qq * 4 + r] = __shfl(myv[4 + r], src);
      }
    }
  }

  // ---- phase 3: LDS-gather sampling + MFMA GEMM ----
  f32x4 acc[4], accB[4];
#pragma unroll
  for (int ms = 0; ms < 4; ++ms) {
    acc[ms]  = (f32x4){0.f, 0.f, 0.f, 0.f};
    accB[ms] = (f32x4){0.f, 0.f, 0.f, 0.f};
  }

  const short* wqA = wA + q * 512 + col * 8;

#pragma unroll
  for (int j = 0; j < 9; ++j) {
    float o1 = oall[j], o2 = oall[9 + j], mk = oall[18 + j];

    float pxf = o1 + (float)(w + (j % 3) - 1);
    float pyf = o2 + (float)(h + (j / 3) - 1);
    float fx = floorf(pxf), fy = floorf(pyf);
    int   x0 = (int)fx,   y0 = (int)fy;
    float ax = pxf - fx, ay = pyf - fy;
    float bx = 1.f - ax, by = 1.f - ay;

    // validity factorizes per-axis: zero the axis weight instead of the product
    bx = (x0 >= 0  && x0 < HW_)     ? bx : 0.f;
    ax = (x0 >= -1 && x0 < HW_ - 1) ? ax : 0.f;
    by = (y0 >= 0  && y0 < HW_)     ? by : 0.f;
    ay = (y0 >= -1 && y0 < HW_ - 1) ? ay : 0.f;
    float bym = by * mk, aym = ay * mk;
    float u00 = bym * bx, u01 = bym * ax;
    float u10 = aym * bx, u11 = aym * ax;
    f32x2 U00 = {u00, u00}, U01 = {u01, u01};
    f32x2 U10 = {u10, u10}, U11 = {u11, u11};

    unsigned F0u[4], F1u[4];
    bool intile = (o1 >= -1.f) && (o1 < 1.f) && (o2 >= -1.f) && (o2 < 1.f);
    if (intile) {
      // in-tile guarantee: r0 in [0,4], c0 in [2,36] -> no clamps; r1=r0+1,
      // c1=c0+1 -> all 8 reads are one base + compile-time immediates.
      // 16B alignment holds: (r0*TC_+c0)*PIT_ + q*4 is a multiple of 4 dw.
      int r0 = y0 - (h0 - 2), c0 = x0 - (w0 - 4);
      const unsigned* t00 = &lds_[(r0 * TC_ + c0) * PIT_ + q * 4];
      u32x4 A00 = *(const u32x4*)(t00);
      u32x4 A01 = *(const u32x4*)(t00 + PIT_);
      u32x4 A10 = *(const u32x4*)(t00 + TC_ * PIT_);
      u32x4 A11 = *(const u32x4*)(t00 + TC_ * PIT_ + PIT_);
      u32x4 B00 = *(const u32x4*)(t00 + 16);
      u32x4 B01 = *(const u32x4*)(t00 + PIT_ + 16);
      u32x4 B10 = *(const u32x4*)(t00 + TC_ * PIT_ + 16);
      u32x4 B11 = *(const u32x4*)(t00 + TC_ * PIT_ + PIT_ + 16);
#pragma unroll
      for (int i = 0; i < 4; ++i) {
        f32x2 v0 = up2d(A00[i]) * U00 + up2d(A01[i]) * U01
                 + up2d(A10[i]) * U10 + up2d(A11[i]) * U11;   // v_pk_fma_f32
        F0u[i] = PK2(v0.x, v0.y);
        f32x2 v1 = up2d(B00[i]) * U00 + up2d(B01[i]) * U01
                 + up2d(B10[i]) * U10 + up2d(B11[i]) * U11;
        F1u[i] = PK2(v1.x, v1.y);
      }
    } else {
      // rare fallback: gather straight from f32 NCHW x (clamps only here)
      int xc0 = min(max(x0, 0), HW_ - 1), xc1 = min(max(x0 + 1, 0), HW_ - 1);
      int yc0 = min(max(y0, 0), HW_ - 1), yc1 = min(max(y0 + 1, 0), HW_ - 1);
      int g00 = yc0 * HW_ + xc0, g01 = yc0 * HW_ + xc1;
      int g10 = yc1 * HW_ + xc0, g11 = yc1 * HW_ + xc1;
      for (int hB = 0; hB < 2; ++hB) {
        for (int ii = 0; ii < 4; ++ii) {
          int c0i = hB * 32 + q * 8 + 2 * ii;
          const float* pc = xB + c0i * IMG_;
          const float* pd = pc + IMG_;
          float va = u00 * pc[g00] + u01 * pc[g01] + u10 * pc[g10] + u11 * pc[g11];
          float vb = u00 * pd[g00] + u01 * pd[g01] + u10 * pd[g10] + u11 * pd[g11];
          if (hB) F1u[ii] = PK2(va, vb); else F0u[ii] = PK2(va, vb);
        }
      }
    }

    union { unsigned u[4]; s16x8 v; } F0, F1;
#pragma unroll
    for (int i = 0; i < 4; ++i) { F0.u[i] = F0u[i]; F1.u[i] = F1u[i]; }

    const short* wj = wqA + j * 4096;
#pragma unroll
    for (int ms = 0; ms < 4; ++ms) {
      s16x8 a0 = *(const s16x8*)(wj + ms * 128);
      acc[ms] = __builtin_amdgcn_mfma_f32_16x16x32_bf16(a0, F0.v, acc[ms], 0, 0, 0);
    }
#pragma unroll
    for (int ms = 0; ms < 4; ++ms) {
      s16x8 a1 = *(const s16x8*)(wj + 2048 + ms * 128);
      accB[ms] = __builtin_amdgcn_mfma_f32_16x16x32_bf16(a1, F1.v, accB[ms], 0, 0, 0);
    }
  }

  float* op = out + (size_t)bi * (CIN_ * IMG_) + p;
#pragma unroll
  for (int ms = 0; ms < 4; ++ms) {
    f32x4 r = acc[ms] + accB[ms];
#pragma unroll
    for (int rr = 0; rr < 4; ++rr)
      op[(ms * 16 + q * 4 + rr) * IMG_] = r[rr];
  }
}

extern "C" void kernel_launch(void* const* d_in, const int* in_sizes, int n_in,
                              void* d_out, int out_size, void* d_ws, size_t ws_size,
                              hipStream_t stream) {
  const float* x      = (const float*)d_in[0];
  const float* w_off  = (const float*)d_in[1];
  const float* b_off  = (const float*)d_in[2];
  const float* w_conv = (const float*)d_in[3];
  float* out = (float*)d_out;

  char* ws = (char*)d_ws;
  short* wOf = (short*)(ws);
  short* wA  = (short*)(ws + 36864);

  hipLaunchKernelGGL(wprep, dim3(144),  dim3(256), 0, stream, w_off, w_conv, wOf, wA);
  hipLaunchKernelGGL(dfuse, dim3(2048), dim3(256), 0, stream, x, wOf, b_off, wA, out);
}

// Round 7
// 124.921 us; speedup vs baseline: 1.2993x; 1.0115x over previous
//
#include <hip/hip_runtime.h>
#include <math.h>

#define HW_   128
#define CIN_  64
#define IMG_  (HW_ * HW_)       // 16384

// 2 output rows x 32 output cols per block
#define TR_    6                // tile rows  [h0-2 .. h0+3]
#define TC_    40               // tile cols  [w0-4 .. w0+35]
#define PIT_   36               // dwords per pixel (64ch bf16 = 32 dw + 4 pad)
                                // MUST be mult of 4: keeps every u32x4 LDS access 16B-aligned
#define TILEDW (TR_ * TC_ * PIT_)   // 8640 dw = 34560 B -> 4 blocks/CU
#define NU_    (TR_ * 8 * 10)       // 480 staging units (r, cq, cc)

typedef short    s16x8 __attribute__((ext_vector_type(8)));
typedef float    f32x4 __attribute__((ext_vector_type(4)));
typedef float    f32x2 __attribute__((ext_vector_type(2)));
typedef unsigned u32x4 __attribute__((ext_vector_type(4)));

__device__ __forceinline__ short f2bf(float f) {
  union { float f; unsigned i; } v; v.f = f;
  unsigned r = (v.i + 0x7fffu + ((v.i >> 16) & 1u)) >> 16;   // RNE
  return (short)r;
}

#if defined(__has_builtin)
#if __has_builtin(__builtin_amdgcn_cvt_pk_bf16_f32)
#define HAVE_CVT_PK_BF16 1
#endif
#endif

// pack two f32 -> bf16 pair (lo=a, hi=b)
__device__ __forceinline__ unsigned PK2(float a, float b) {
#ifdef HAVE_CVT_PK_BF16
  typedef __bf16 bf16x2_t __attribute__((ext_vector_type(2)));
  union { bf16x2_t v; unsigned u; } cv;
  cv.v = __builtin_amdgcn_cvt_pk_bf16_f32(a, b);
  return cv.u;
#else
  union { float f; unsigned u; } ua, ub; ua.f = a; ub.f = b;
  unsigned ra = ua.u + 0x7fffu + ((ua.u >> 16) & 1u);
  unsigned rb = ub.u + 0x7fffu + ((ub.u >> 16) & 1u);
  return __builtin_amdgcn_perm(rb, ra, 0x07060302u);
#endif
}

// dirty-hi f32x2 unpack of a bf16 pair: elem0 exact (d<<16), elem1 keeps the
// junk low 16 mantissa bits (rel err ~2^-16, far below the 2^-9 bf16 repack
// rounding). 1 VALU op per dword; blend chains on f32x2 emit v_pk_fma_f32.
__device__ __forceinline__ f32x2 up2d(unsigned d) {
  union { unsigned u; float f; } lo, hi;
  lo.u = d << 16; hi.u = d;
  return (f32x2){lo.f, hi.f};
}

// ws layout (bytes):
//   [0,     36864)  wOf bf16 [j:9][ks:2][q:4][m:32][i:8]  (A-frag order, m>=27 zero)
//   [36864, 110592) wA  bf16 [j:9][ks:2][q:4][o:64][i:8]  (A-frag order)

__global__ __launch_bounds__(256) void wprep(const float* __restrict__ w_off,
                                             const float* __restrict__ w_conv,
                                             short* __restrict__ wOf,
                                             short* __restrict__ wA) {
  int t = blockIdx.x * 256 + threadIdx.x;
  if (t < 36864) {
    int i = t & 7, o = (t >> 3) & 63, q = (t >> 9) & 3, ks = (t >> 11) & 1, j = t >> 12;
    int c = ks * 32 + q * 8 + i;
    wA[t] = f2bf(w_conv[o * 576 + c * 9 + j]);
  }
  if (t < 18432) {
    int i = t & 7, m = (t >> 3) & 31, q = (t >> 8) & 3, ks = (t >> 10) & 1, j = t >> 11;
    int c = ks * 32 + q * 8 + i;
    wOf[t] = (m < 27) ? f2bf(w_off[(m * 64 + c) * 9 + j]) : (short)0;
  }
}

// Fully fused (round-3 structure): stage f32 NCHW -> bf16 NHWC halo tile in
// LDS (zero-filled OOB, one barrier), offset conv (MFMA), shuffle-exchange
// offsets, LDS-gather sampling + MFMA GEMM (f32 global fallback for |o|>=1).
// Round-7 delta: staging unit = (row, channel-QUAD, 4-px chunk) so each pixel
// gets ONE ds_write_b128 (contiguous 4 dwords) instead of 4 strided b32
// writes. b32 writes were ~5-way bank-conflicted (bank = (16cc+4pxi+cp)%32,
// 10-lane cc-bands on 2 banks) = ~8.6us/kernel; b128 column index
// (pxidx+cq)%8 is ~uniform -> near-conflict-free. T14 batching preserved
// (all 16 loads of both units issued before converts/writes).
__global__ __launch_bounds__(256)
__attribute__((amdgpu_waves_per_eu(4)))
void dfuse(const float* __restrict__ x,
           const short* __restrict__ wOf,
           const float* __restrict__ b_off,
           const short* __restrict__ wA,
           float* __restrict__ out) {
  __shared__ __align__(16) unsigned lds_[TILEDW];

  int bi  = blockIdx.x & 7;        // XCD-aligned image index
  int tid = blockIdx.x >> 3;       // 0..255 tile within image
  int h0  = (tid >> 2) << 1;       // 0,2,..,126
  int w0  = (tid & 3) << 5;        // 0,32,64,96
  int t   = threadIdx.x;
  int wv  = t >> 6, l = t & 63;
  int col = l & 15, q = l >> 4;
  int px_local = wv * 16 + col;    // 0..63
  int rl  = px_local >> 5;         // local row 0..1
  int cl  = px_local & 31;         // local col 0..31
  int h   = h0 + rl;
  int w   = w0 + cl;
  int p   = h * HW_ + w;

  const float* xB = x + (size_t)bi * (CIN_ * IMG_);

  // ---- stage halo tile: rows h0-2..h0+3, cols w0-4..w0+35, 64 ch bf16 ----
  // unit u: cc = u%10 (4-px chunk), cq = (u/10)%8 (channels 8cq..8cq+7),
  // r = u/80. Unit A = t, unit B = t+256 (first 224 threads only).
  {
    f32x4 L0a[4], L1a[4], L0b[4], L1b[4];
    int sda, sdb;
    unsigned ma, mb;
    {
      int u = t;
      int cc = u % 10, cq = (u / 10) & 7, r = u / 80;
      int y  = h0 - 2 + r;
      int ys = min(max(y, 0), HW_ - 1);
      int xg0 = w0 - 4 + cc * 4;
      int xs  = min(max(xg0, 0), HW_ - 4);             // 16B-aligned
      ma = ((y >= 0) && (y < HW_) && (xg0 >= 0) && (xg0 < HW_)) ? 0xffffffffu : 0u;
      const float* s0 = xB + (size_t)(8 * cq) * IMG_ + ys * HW_ + xs;
#pragma unroll
      for (int i = 0; i < 4; ++i) {
        L0a[i] = *(const f32x4*)(s0 + (2 * i) * IMG_);
        L1a[i] = *(const f32x4*)(s0 + (2 * i + 1) * IMG_);
      }
      sda = (r * TC_ + cc * 4) * PIT_ + cq * 4;
    }
    bool hasB = (t + 256) < NU_;
    {
      int u = hasB ? (t + 256) : 0;
      int cc = u % 10, cq = (u / 10) & 7, r = u / 80;
      int y  = h0 - 2 + r;
      int ys = min(max(y, 0), HW_ - 1);
      int xg0 = w0 - 4 + cc * 4;
      int xs  = min(max(xg0, 0), HW_ - 4);
      mb = ((y >= 0) && (y < HW_) && (xg0 >= 0) && (xg0 < HW_)) ? 0xffffffffu : 0u;
      const float* s0 = xB + (size_t)(8 * cq) * IMG_ + ys * HW_ + xs;
#pragma unroll
      for (int i = 0; i < 4; ++i) {
        L0b[i] = *(const f32x4*)(s0 + (2 * i) * IMG_);
        L1b[i] = *(const f32x4*)(s0 + (2 * i + 1) * IMG_);
      }
      sdb = (r * TC_ + cc * 4) * PIT_ + cq * 4;
    }
#pragma unroll
    for (int pxi = 0; pxi < 4; ++pxi) {
      u32x4 v;
#pragma unroll
      for (int i = 0; i < 4; ++i) v[i] = PK2(L0a[i][pxi], L1a[i][pxi]) & ma;
      *(u32x4*)(lds_ + sda + pxi * PIT_) = v;
    }
    if (hasB) {
#pragma unroll
      for (int pxi = 0; pxi < 4; ++pxi) {
        u32x4 v;
#pragma unroll
        for (int i = 0; i < 4; ++i) v[i] = PK2(L0b[i][pxi], L1b[i][pxi]) & mb;
        *(u32x4*)(lds_ + sdb + pxi * PIT_) = v;
      }
    }
  }
  __syncthreads();

  // ---- phase 1: offset conv from tile (tile is zero-padded: no masking) ----
  float oall[32];
  {
    const short* wq = wOf + q * 256 + col * 8;
    f32x4 a0v = {0.f, 0.f, 0.f, 0.f};
    f32x4 a1v = {0.f, 0.f, 0.f, 0.f};
    f32x4 a0w = {0.f, 0.f, 0.f, 0.f};
    f32x4 a1w = {0.f, 0.f, 0.f, 0.f};
    const unsigned* tb = &lds_[((rl + 2) * TC_ + (cl + 4)) * PIT_ + q * 4];
#pragma unroll
    for (int j = 0; j < 9; ++j) {
      int dy = j / 3 - 1, dx = j % 3 - 1;
      const unsigned* tp = tb + (dy * TC_ + dx) * PIT_;   // compile-time imm
      union { u32x4 u; s16x8 v; } B0, B1;
      B0.u = *(const u32x4*)tp;
      B1.u = *(const u32x4*)(tp + 16);
      const short* wj = wq + j * 2048;
      s16x8 a00 = *(const s16x8*)(wj);
      s16x8 a01 = *(const s16x8*)(wj + 128);
      s16x8 a10 = *(const s16x8*)(wj + 1024);
      s16x8 a11 = *(const s16x8*)(wj + 1024 + 128);
      a0v = __builtin_amdgcn_mfma_f32_16x16x32_bf16(a00, B0.v, a0v, 0, 0, 0);
      a1v = __builtin_amdgcn_mfma_f32_16x16x32_bf16(a01, B0.v, a1v, 0, 0, 0);
      a0w = __builtin_amdgcn_mfma_f32_16x16x32_bf16(a10, B1.v, a0w, 0, 0, 0);
      a1w = __builtin_amdgcn_mfma_f32_16x16x32_bf16(a11, B1.v, a1w, 0, 0, 0);
    }
    a0v += a0w;
    a1v += a1w;
    // bias + sigmoid by producer lanes, then wave-local shuffle exchange
    float myv[8];
#pragma unroll
    for (int r = 0; r < 4; ++r) myv[r] = a0v[r] + b_off[q * 4 + r];
#pragma unroll
    for (int r = 0; r < 4; ++r) {
      int ch = 16 + q * 4 + r;
      float bo = b_off[min(ch, 26)];
      float v = a1v[r] + bo;
      myv[4 + r] = (ch >= 18) ? (1.f / (1.f + __expf(-v))) : v;
    }
#pragma unroll
    for (int qq = 0; qq < 4; ++qq) {
      int src = qq * 16 + col;
#pragma unroll
      for (int r = 0; r < 4; ++r) {
        oall[qq * 4 + r]      = __shfl(myv[r], src);
        oall[16 + qq * 4 + r] = __shfl(myv[4 + r], src);
      }
    }
  }

  // ---- phase 3: LDS-gather sampling + MFMA GEMM ----
  f32x4 acc[4], accB[4];
#pragma unroll
  for (int ms = 0; ms < 4; ++ms) {
    acc[ms]  = (f32x4){0.f, 0.f, 0.f, 0.f};
    accB[ms] = (f32x4){0.f, 0.f, 0.f, 0.f};
  }

  const short* wqA = wA + q * 512 + col * 8;

#pragma unroll
  for (int j = 0; j < 9; ++j) {
    float o1 = oall[j], o2 = oall[9 + j], mk = oall[18 + j];

    float pxf = o1 + (float)(w + (j % 3) - 1);
    float pyf = o2 + (float)(h + (j / 3) - 1);
    float fx = floorf(pxf), fy = floorf(pyf);
    int   x0 = (int)fx,   y0 = (int)fy;
    float ax = pxf - fx, ay = pyf - fy;
    float bx = 1.f - ax, by = 1.f - ay;

    // validity factorizes per-axis: zero the axis weight instead of the product
    bx = (x0 >= 0  && x0 < HW_)     ? bx : 0.f;
    ax = (x0 >= -1 && x0 < HW_ - 1) ? ax : 0.f;
    by = (y0 >= 0  && y0 < HW_)     ? by : 0.f;
    ay = (y0 >= -1 && y0 < HW_ - 1) ? ay : 0.f;
    float bym = by * mk, aym = ay * mk;
    float u00 = bym * bx, u01 = bym * ax;
    float u10 = aym * bx, u11 = aym * ax;
    f32x2 U00 = {u00, u00}, U01 = {u01, u01};
    f32x2 U10 = {u10, u10}, U11 = {u11, u11};

    unsigned F0u[4], F1u[4];
    bool intile = (o1 >= -1.f) && (o1 < 1.f) && (o2 >= -1.f) && (o2 < 1.f);
    if (intile) {
      // in-tile guarantee: r0 in [0,4], c0 in [2,36] -> no clamps; r1=r0+1,
      // c1=c0+1 -> all 8 reads are one base + compile-time immediates.
      // 16B alignment holds: (r0*TC_+c0)*PIT_ + q*4 is a multiple of 4 dw.
      int r0 = y0 - (h0 - 2), c0 = x0 - (w0 - 4);
      const unsigned* t00 = &lds_[(r0 * TC_ + c0) * PIT_ + q * 4];
      u32x4 A00 = *(const u32x4*)(t00);
      u32x4 A01 = *(const u32x4*)(t00 + PIT_);
      u32x4 A10 = *(const u32x4*)(t00 + TC_ * PIT_);
      u32x4 A11 = *(const u32x4*)(t00 + TC_ * PIT_ + PIT_);
      u32x4 B00 = *(const u32x4*)(t00 + 16);
      u32x4 B01 = *(const u32x4*)(t00 + PIT_ + 16);
      u32x4 B10 = *(const u32x4*)(t00 + TC_ * PIT_ + 16);
      u32x4 B11 = *(const u32x4*)(t00 + TC_ * PIT_ + PIT_ + 16);
#pragma unroll
      for (int i = 0; i < 4; ++i) {
        f32x2 v0 = up2d(A00[i]) * U00 + up2d(A01[i]) * U01
                 + up2d(A10[i]) * U10 + up2d(A11[i]) * U11;   // v_pk_fma_f32
        F0u[i] = PK2(v0.x, v0.y);
        f32x2 v1 = up2d(B00[i]) * U00 + up2d(B01[i]) * U01
                 + up2d(B10[i]) * U10 + up2d(B11[i]) * U11;
        F1u[i] = PK2(v1.x, v1.y);
      }
    } else {
      // rare fallback: gather straight from f32 NCHW x (clamps only here)
      int xc0 = min(max(x0, 0), HW_ - 1), xc1 = min(max(x0 + 1, 0), HW_ - 1);
      int yc0 = min(max(y0, 0), HW_ - 1), yc1 = min(max(y0 + 1, 0), HW_ - 1);
      int g00 = yc0 * HW_ + xc0, g01 = yc0 * HW_ + xc1;
      int g10 = yc1 * HW_ + xc0, g11 = yc1 * HW_ + xc1;
      for (int hB = 0; hB < 2; ++hB) {
        for (int ii = 0; ii < 4; ++ii) {
          int c0i = hB * 32 + q * 8 + 2 * ii;
          const float* pc = xB + c0i * IMG_;
          const float* pd = pc + IMG_;
          float va = u00 * pc[g00] + u01 * pc[g01] + u10 * pc[g10] + u11 * pc[g11];
          float vb = u00 * pd[g00] + u01 * pd[g01] + u10 * pd[g10] + u11 * pd[g11];
          if (hB) F1u[ii] = PK2(va, vb); else F0u[ii] = PK2(va, vb);
        }
      }
    }

    union { unsigned u[4]; s16x8 v; } F0, F1;
#pragma unroll
    for (int i = 0; i < 4; ++i) { F0.u[i] = F0u[i]; F1.u[i] = F1u[i]; }

    const short* wj = wqA + j * 4096;
#pragma unroll
    for (int ms = 0; ms < 4; ++ms) {
      s16x8 a0 = *(const s16x8*)(wj + ms * 128);
      acc[ms] = __builtin_amdgcn_mfma_f32_16x16x32_bf16(a0, F0.v, acc[ms], 0, 0, 0);
    }
#pragma unroll
    for (int ms = 0; ms < 4; ++ms) {
      s16x8 a1 = *(const s16x8*)(wj + 2048 + ms * 128);
      accB[ms] = __builtin_amdgcn_mfma_f32_16x16x32_bf16(a1, F1.v, accB[ms], 0, 0, 0);
    }
  }

  float* op = out + (size_t)bi * (CIN_ * IMG_) + p;
#pragma unroll
  for (int ms = 0; ms < 4; ++ms) {
    f32x4 r = acc[ms] + accB[ms];
#pragma unroll
    for (int rr = 0; rr < 4; ++rr)
      op[(ms * 16 + q * 4 + rr) * IMG_] = r[rr];
  }
}

extern "C" void kernel_launch(void* const* d_in, const int* in_sizes, int n_in,
                              void* d_out, int out_size, void* d_ws, size_t ws_size,
                              hipStream_t stream) {
  const float* x      = (const float*)d_in[0];
  const float* w_off  = (const float*)d_in[1];
  const float* b_off  = (const float*)d_in[2];
  const float* w_conv = (const float*)d_in[3];
  float* out = (float*)d_out;

  char* ws = (char*)d_ws;
  short* wOf = (short*)(ws);
  short* wA  = (short*)(ws + 36864);

  hipLaunchKernelGGL(wprep, dim3(144),  dim3(256), 0, stream, w_off, w_conv, wOf, wA);
  hipLaunchKernelGGL(dfuse, dim3(2048), dim3(256), 0, stream, x, wOf, b_off, wA, out);
}